// Round 1
// baseline (65.095 us; speedup 1.0000x reference)
//
#include <hip/hip_runtime.h>
#include <math.h>

#define BB 512

// One block per anchor row j. Computes the row's contribution to the
// triplet semi-hard loss sum and the row's positive-pair count.
__global__ __launch_bounds__(256) void tshl_row_kernel(
    const float* __restrict__ pdist, const int* __restrict__ target,
    float* __restrict__ row_sum, float* __restrict__ row_cnt)
{
    __shared__ float srow[BB];
    __shared__ int   slab[BB];
    __shared__ float rmax[256];
    __shared__ float rmin[256];

    const int j = blockIdx.x;
    const int t = threadIdx.x;

    // Stage row j of pdist and all labels into LDS.
    for (int k = t; k < BB; k += 256) {
        srow[k] = pdist[j * BB + k];
        slab[k] = target[k];
    }
    __syncthreads();

    const int myLab = slab[j];

    // Phase 1: neg_inside(j) = max{d[j,k] : label[k] != label[j]},
    // fallback to row min when no unequal label exists (masked_maximum semantics).
    float locmax = -INFINITY;   // over label-unequal entries
    float locmin =  INFINITY;   // over all entries
    for (int k = t; k < BB; k += 256) {
        float d = srow[k];
        locmin = fminf(locmin, d);
        if (slab[k] != myLab) locmax = fmaxf(locmax, d);
    }
    rmax[t] = locmax;
    rmin[t] = locmin;
    __syncthreads();
    for (int s = 128; s > 0; s >>= 1) {
        if (t < s) {
            rmax[t] = fmaxf(rmax[t], rmax[t + s]);
            rmin[t] = fminf(rmin[t], rmin[t + s]);
        }
        __syncthreads();
    }
    const float neg_in = (rmax[0] == -INFINITY) ? rmin[0] : rmax[0];
    __syncthreads();   // everyone has read rmax[0]/rmin[0] before LDS reuse

    // Phase 2: each thread owns columns i = t and t+256.
    float psum = 0.0f;
    float pcnt = 0.0f;
    for (int i = t; i < BB; i += 256) {
        if (i != j && slab[i] == myLab) {
            pcnt += 1.0f;
            const float dpos = srow[i];
            float m = INFINITY;
            int exists = 0;
            for (int k = 0; k < BB; ++k) {
                const float d = srow[k];
                if (slab[k] != myLab && d > dpos) {
                    m = fminf(m, d);
                    exists = 1;
                }
            }
            const float shn = exists ? m : neg_in;
            const float loss = 1.0f + dpos - shn;
            psum += fmaxf(loss, 0.0f);
        }
    }

    // Phase 3: block reduce (sum) into row_sum/row_cnt.
    rmax[t] = psum;
    rmin[t] = pcnt;
    __syncthreads();
    for (int s = 128; s > 0; s >>= 1) {
        if (t < s) {
            rmax[t] += rmax[t + s];
            rmin[t] += rmin[t + s];
        }
        __syncthreads();
    }
    if (t == 0) {
        row_sum[j] = rmax[0];
        row_cnt[j] = rmin[0];
    }
}

// Final reduce over 512 rows: out = sum / max(count, 1).
__global__ __launch_bounds__(512) void tshl_final_kernel(
    const float* __restrict__ row_sum, const float* __restrict__ row_cnt,
    float* __restrict__ out)
{
    __shared__ float s1[BB];
    __shared__ float s2[BB];
    const int t = threadIdx.x;
    s1[t] = row_sum[t];
    s2[t] = row_cnt[t];
    __syncthreads();
    for (int s = 256; s > 0; s >>= 1) {
        if (t < s) {
            s1[t] += s1[t + s];
            s2[t] += s2[t + s];
        }
        __syncthreads();
    }
    if (t == 0) out[0] = s1[0] / fmaxf(s2[0], 1.0f);
}

extern "C" void kernel_launch(void* const* d_in, const int* in_sizes, int n_in,
                              void* d_out, int out_size, void* d_ws, size_t ws_size,
                              hipStream_t stream) {
    const float* pdist  = (const float*)d_in[0];
    const int*   target = (const int*)d_in[1];   // harness delivers integer inputs as int32
    float* ws      = (float*)d_ws;
    float* row_sum = ws;
    float* row_cnt = ws + BB;
    float* out     = (float*)d_out;

    tshl_row_kernel<<<BB, 256, 0, stream>>>(pdist, target, row_sum, row_cnt);
    tshl_final_kernel<<<1, BB, 0, stream>>>(row_sum, row_cnt, out);
}

// Round 2
// 13.624 us; speedup vs baseline: 4.7779x; 4.7779x over previous
//
#include <hip/hip_runtime.h>
#include <math.h>

#define BB 512
#define NT 256
#define NW 4

// One block (256 threads, 4 waves) per anchor row j.
__global__ __launch_bounds__(256) void tshl_row_kernel(
    const float* __restrict__ pdist, const int* __restrict__ target,
    float* __restrict__ row_sum, float* __restrict__ row_cnt)
{
    __shared__ float srow[BB];
    __shared__ int   slab[BB];
    __shared__ float swmax[NW], swmin[NW];
    __shared__ int   scnt[2 * NW];
    __shared__ int   spos[BB];
    __shared__ float spart[BB][NW];   // per-positive per-wave masked-min partials
    __shared__ float ssum[NW];

    const int j    = blockIdx.x;
    const int t    = threadIdx.x;
    const int w    = t >> 6;
    const int lane = t & 63;

    // Stage row j and labels (each thread owns columns t and t+256).
    srow[t]       = pdist[j * BB + t];
    srow[t + 256] = pdist[j * BB + t + 256];
    slab[t]       = target[t];
    slab[t + 256] = target[t + 256];
    __syncthreads();

    const int   myLab = slab[j];
    const float d1 = srow[t], d2 = srow[t + 256];
    const int   l1 = slab[t], l2 = slab[t + 256];
    const bool  n1 = (l1 != myLab), n2 = (l2 != myLab);

    // Phase 1: wave-parallel row reductions.
    // lmax over label-unequal entries; lmin over all (masked_maximum fallback).
    float lmax = -INFINITY;
    float lmin = fminf(d1, d2);
    if (n1) lmax = d1;
    if (n2) lmax = fmaxf(lmax, d2);
    #pragma unroll
    for (int m = 32; m; m >>= 1) {
        lmax = fmaxf(lmax, __shfl_xor(lmax, m));
        lmin = fminf(lmin, __shfl_xor(lmin, m));
    }
    if (lane == 0) { swmax[w] = lmax; swmin[w] = lmin; }

    // Ordered positive list via ballot + popcount prefix (deterministic, no atomics).
    const bool f1 = (l1 == myLab) && (t != j);
    const bool f2 = (l2 == myLab) && (t + 256 != j);
    const unsigned long long m1 = __ballot(f1);
    const unsigned long long m2 = __ballot(f2);
    if (lane == 0) { scnt[w] = __popcll(m1); scnt[NW + w] = __popcll(m2); }
    __syncthreads();

    int npos = 0;
    int pre[2 * NW];
    #pragma unroll
    for (int e = 0; e < 2 * NW; ++e) { pre[e] = npos; npos += scnt[e]; }
    const unsigned long long lmask = (1ULL << lane) - 1ULL;
    if (f1) spos[pre[w]      + __popcll(m1 & lmask)] = t;
    if (f2) spos[pre[NW + w] + __popcll(m2 & lmask)] = t + 256;

    const float rmaxv = fmaxf(fmaxf(swmax[0], swmax[1]), fmaxf(swmax[2], swmax[3]));
    const float rminv = fminf(fminf(swmin[0], swmin[1]), fminf(swmin[2], swmin[3]));
    const float neg_in = (rmaxv == -INFINITY) ? rminv : rmaxv;
    __syncthreads();   // spos visible to all waves

    // Phase 2: per positive, wave-local masked min (no barriers in loop).
    for (int q = 0; q < npos; ++q) {
        const int   i    = spos[q];
        const float dpos = srow[i];
        float c = INFINITY;
        if (n1 && d1 > dpos) c = d1;
        if (n2 && d2 > dpos) c = fminf(c, d2);
        #pragma unroll
        for (int m = 32; m; m >>= 1) c = fminf(c, __shfl_xor(c, m));
        if (lane == 0) spart[q][w] = c;
    }
    __syncthreads();

    // Phase 3: finalize each positive, accumulate loss.
    float psum = 0.0f;
    for (int q = t; q < npos; q += NT) {
        const float mv = fminf(fminf(spart[q][0], spart[q][1]),
                               fminf(spart[q][2], spart[q][3]));
        const float dpos = srow[spos[q]];
        const float shn  = (mv < INFINITY) ? mv : neg_in;
        psum += fmaxf(1.0f + dpos - shn, 0.0f);
    }
    #pragma unroll
    for (int m = 32; m; m >>= 1) psum += __shfl_xor(psum, m);
    if (lane == 0) ssum[w] = psum;
    __syncthreads();
    if (t == 0) {
        row_sum[j] = ssum[0] + ssum[1] + ssum[2] + ssum[3];
        row_cnt[j] = (float)npos;
    }
}

// Final reduce over 512 rows: out = sum / max(count, 1).
__global__ __launch_bounds__(512) void tshl_final_kernel(
    const float* __restrict__ row_sum, const float* __restrict__ row_cnt,
    float* __restrict__ out)
{
    __shared__ float s1[NW * 2], s2[NW * 2];
    const int t = threadIdx.x;
    const int w = t >> 6;
    const int lane = t & 63;
    float a = row_sum[t];
    float b = row_cnt[t];
    #pragma unroll
    for (int m = 32; m; m >>= 1) {
        a += __shfl_xor(a, m);
        b += __shfl_xor(b, m);
    }
    if (lane == 0) { s1[w] = a; s2[w] = b; }
    __syncthreads();
    if (t == 0) {
        float sum = 0.0f, cnt = 0.0f;
        #pragma unroll
        for (int e = 0; e < NW * 2; ++e) { sum += s1[e]; cnt += s2[e]; }
        out[0] = sum / fmaxf(cnt, 1.0f);
    }
}

extern "C" void kernel_launch(void* const* d_in, const int* in_sizes, int n_in,
                              void* d_out, int out_size, void* d_ws, size_t ws_size,
                              hipStream_t stream) {
    const float* pdist  = (const float*)d_in[0];
    const int*   target = (const int*)d_in[1];
    float* ws      = (float*)d_ws;
    float* row_sum = ws;
    float* row_cnt = ws + BB;
    float* out     = (float*)d_out;

    tshl_row_kernel<<<BB, NT, 0, stream>>>(pdist, target, row_sum, row_cnt);
    tshl_final_kernel<<<1, BB, 0, stream>>>(row_sum, row_cnt, out);
}